// Round 7
// baseline (181.911 us; speedup 1.0000x reference)
//
#include <hip/hip_runtime.h>
#include <math.h>

#define N_NODES 30000
#define K_NBR   16
#define C_IN    256
#define C_OUT   128
#define KS      9
#define S_MB    17
#define REPS    8     // DIAGNOSTIC amplification (idempotent) — remove next round

typedef __attribute__((ext_vector_type(4))) float f32x4;
typedef __attribute__((ext_vector_type(2))) float f32x2;
typedef __attribute__((ext_vector_type(8))) short bf16x8;

static __device__ __forceinline__ ushort f2bf(float f) {
    uint u = __builtin_bit_cast(uint, f);
    u += 0x7fffu + ((u >> 16) & 1u);          // round-to-nearest-even
    return (ushort)(u >> 16);
}

// ---------------------------------------------------------------------------
// Prep (unamplified): Bf fragment conversion + Ws/Cd constants.
// ---------------------------------------------------------------------------
__global__ __launch_bounds__(256)
void pcg_prep(const float* __restrict__ W_lin,
              const float* __restrict__ W_res,
              const float* __restrict__ weight,
              const float* __restrict__ b_lin,
              const float* __restrict__ bias,
              const float* __restrict__ b_res,
              ushort* __restrict__ Bf,
              float* __restrict__ Ws,
              float* __restrict__ Cd) {
    if (blockIdx.x == 32) {
        int d = threadIdx.x;
        if (d >= C_OUT) return;
        float freq = powf(10000.0f, -(float)(d & ~1) / (float)C_OUT);
        float ws = 0.f, p = 0.f;
        for (int s = 0; s < S_MB; ++s) {
            int idx = (int)floorf((float)s * (9.0f / 17.0f));
            ws += weight[d * KS + idx];
            float ang = (float)idx * freq;
            p += (d & 1) ? cosf(ang) : sinf(ang);
        }
        Ws[d] = ws;
        Cd[d] = ws * ((float)(K_NBR + 1) * b_lin[d] + p) + bias[d] + b_res[d];
        return;
    }
    const int tt     = blockIdx.x * 256 + threadIdx.x;   // 0..8191
    const int col_lo = tt & 15;
    const int ksub   = (tt >> 4) & 3;
    const int colhi  = (tt >> 6) & 15;
    const int kc     = tt >> 10;
    const int col    = colhi * 16 + col_lo;
    const int k0     = kc * 32 + ksub * 8;
    const float* Wr = (col < C_OUT)
        ? &W_lin[(size_t)col * C_IN + k0]
        : &W_res[(size_t)(col - C_OUT) * C_IN + k0];
    const f32x4 w0 = *reinterpret_cast<const f32x4*>(Wr);
    const f32x4 w1 = *reinterpret_cast<const f32x4*>(Wr + 4);
    ushort b[8] = { f2bf(w0.x), f2bf(w0.y), f2bf(w0.z), f2bf(w0.w),
                    f2bf(w1.x), f2bf(w1.y), f2bf(w1.z), f2bf(w1.w) };
    *reinterpret_cast<uint4*>(&Bf[(size_t)tt * 8]) =
        *reinterpret_cast<const uint4*>(b);
}

// ---------------------------------------------------------------------------
// MFMA GEMM + fold, amplified x REPS (identical stores each rep).
// ---------------------------------------------------------------------------
__global__ __launch_bounds__(256)
void pcg_mfma(const float* __restrict__ ndata,
              const ushort* __restrict__ Bf,
              const float* __restrict__ Ws,
              const float* __restrict__ Cd,
              ushort* __restrict__ Gs,
              ushort* __restrict__ Pc) {
    __shared__ short sA[16384];                // 32 frags x 64 x 16B = 32 KB

    const int t  = threadIdx.x;
    const int n0 = blockIdx.x * 64;
    const int wave = t >> 6;
    const int l    = t & 63;
    const int bu   = l ^ (l >> 4);
    const int ch0 = 2 * wave, ch1 = 2 * wave + 1;
    const int ch2 = 8 + 2 * wave, ch3 = 9 + 2 * wave;

    for (int rep = 0; rep < REPS; ++rep) {
        asm volatile("" ::: "memory");

        // ---- stage A tile ----
#pragma unroll
        for (int i = 0; i < 8; ++i) {
            const int v    = i * 256 + t;
            const int row  = v >> 5;
            const int kch  = v & 31;
            f32x4 a0 = {0.f, 0.f, 0.f, 0.f}, a1 = {0.f, 0.f, 0.f, 0.f};
            if (n0 + row < N_NODES) {
                const float* p = &ndata[(size_t)(n0 + row) * C_IN + kch * 8];
                a0 = *reinterpret_cast<const f32x4*>(p);
                a1 = *reinterpret_cast<const f32x4*>(p + 4);
            }
            const int kc   = kch >> 2;
            const int ksub = kch & 3;
            const int f    = kc * 4 + (row >> 4);
            const int up   = (((row & 15) | (ksub << 4)) ^ ksub) ^ ((kc & 1) << 2);
            uint4 w;
            w.x = (uint)f2bf(a0.x) | ((uint)f2bf(a0.y) << 16);
            w.y = (uint)f2bf(a0.z) | ((uint)f2bf(a0.w) << 16);
            w.z = (uint)f2bf(a1.x) | ((uint)f2bf(a1.y) << 16);
            w.w = (uint)f2bf(a1.z) | ((uint)f2bf(a1.w) << 16);
            *reinterpret_cast<uint4*>(&sA[f * 512 + up * 8]) = w;
        }
        __syncthreads();

        f32x4 acc[4][4] = {};

#pragma unroll
        for (int kc = 0; kc < 8; ++kc) {
            const int ux = bu ^ ((kc & 1) << 2);
            bf16x8 a[4];
#pragma unroll
            for (int rg = 0; rg < 4; ++rg)
                a[rg] = *reinterpret_cast<const bf16x8*>(
                            &sA[(kc * 4 + rg) * 512 + ux * 8]);
            bf16x8 b[4];
            b[0] = *reinterpret_cast<const bf16x8*>(&Bf[((size_t)(kc * 16 + ch0) * 64 + l) * 8]);
            b[1] = *reinterpret_cast<const bf16x8*>(&Bf[((size_t)(kc * 16 + ch1) * 64 + l) * 8]);
            b[2] = *reinterpret_cast<const bf16x8*>(&Bf[((size_t)(kc * 16 + ch2) * 64 + l) * 8]);
            b[3] = *reinterpret_cast<const bf16x8*>(&Bf[((size_t)(kc * 16 + ch3) * 64 + l) * 8]);
#pragma unroll
            for (int rg = 0; rg < 4; ++rg)
#pragma unroll
                for (int cg = 0; cg < 4; ++cg)
                    acc[rg][cg] = __builtin_amdgcn_mfma_f32_16x16x32_bf16(
                                      a[rg], b[cg], acc[rg][cg], 0, 0, 0);
        }

        // ---- epilogue ----
        const int cl  = l & 15;
        const int c0  = wave * 32 + cl;
        const int c1  = wave * 32 + 16 + cl;
        const float ws0 = Ws[c0], ws1 = Ws[c1];
        const float cd0 = Cd[c0], cd1 = Cd[c1];
        const int rl  = (l >> 4) * 4;
#pragma unroll
        for (int rg = 0; rg < 4; ++rg) {
#pragma unroll
            for (int j = 0; j < 4; ++j) {
                const int row = n0 + rg * 16 + rl + j;
                if (row < N_NODES) {
                    const float gs0 = ws0 * acc[rg][0][j];
                    const float gs1 = ws1 * acc[rg][1][j];
                    Gs[(size_t)row * C_OUT + c0] = f2bf(gs0);
                    Gs[(size_t)row * C_OUT + c1] = f2bf(gs1);
                    Pc[(size_t)row * C_OUT + c0] = f2bf(gs0 + acc[rg][2][j] + cd0);
                    Pc[(size_t)row * C_OUT + c1] = f2bf(gs1 + acc[rg][3][j] + cd1);
                }
            }
        }
        __syncthreads();   // protect sA against next rep's staging
    }
}

// ---------------------------------------------------------------------------
// Gather, amplified x REPS: accumulate REPS identical passes, scale by 1/REPS
// (exact in fp: x*8 * 0.125 == x). Bit-identical output to single pass.
// ---------------------------------------------------------------------------
__global__ __launch_bounds__(256)
void pcg_gather(const int* __restrict__ neighbors,
                const ushort* __restrict__ Gs,
                const ushort* __restrict__ Pc,
                float* __restrict__ out) {
    __shared__ int snb[64];
    const int t = threadIdx.x;
    if (t < 64) snb[t] = neighbors[(size_t)blockIdx.x * 64 + t];
    __syncthreads();

    const int g = t >> 6;
    const int l = t & 63;
    const int n = blockIdx.x * 4 + g;

    float s0 = 0.f, s1 = 0.f;
    for (int rep = 0; rep < REPS; ++rep) {
        asm volatile("" ::: "memory");
        uint p = *reinterpret_cast<const uint*>(&Pc[(size_t)n * C_OUT + 2 * l]);
        float a0 = __builtin_bit_cast(float, p << 16);
        float a1 = __builtin_bit_cast(float, p & 0xffff0000u);
#pragma unroll
        for (int k = 0; k < K_NBR; ++k) {
            const int m = snb[g * 16 + k];
            uint v = *reinterpret_cast<const uint*>(&Gs[(size_t)m * C_OUT + 2 * l]);
            a0 += __builtin_bit_cast(float, v << 16);
            a1 += __builtin_bit_cast(float, v & 0xffff0000u);
        }
        s0 += a0;
        s1 += a1;
    }

    f32x2 o = {s0 * (1.0f / REPS), s1 * (1.0f / REPS)};
    *reinterpret_cast<f32x2*>(&out[(size_t)n * C_OUT + 2 * l]) = o;
}

// ---------------------------------------------------------------------------
extern "C" void kernel_launch(void* const* d_in, const int* in_sizes, int n_in,
                              void* d_out, int out_size, void* d_ws, size_t ws_size,
                              hipStream_t stream) {
    const float* ndata     = (const float*)d_in[0];
    const int*   neighbors = (const int*)  d_in[1];
    const float* W_lin     = (const float*)d_in[2];
    const float* b_lin     = (const float*)d_in[3];
    const float* weight    = (const float*)d_in[4];
    const float* bias      = (const float*)d_in[5];
    const float* W_res     = (const float*)d_in[6];
    const float* b_res     = (const float*)d_in[7];
    float* out = (float*)d_out;

    ushort* Bf = (ushort*)d_ws;                          // [8192][8] = 128 KB
    ushort* Gq = Bf + 65536;                             // Gs [N][128] = 7.68 MB
    ushort* Pq = Gq + (size_t)N_NODES * C_OUT;           // Pc [N][128] = 7.68 MB
    float*  Ws = (float*)(Pq + (size_t)N_NODES * C_OUT); // [128]
    float*  Cd = Ws + C_OUT;                             // [128]

    pcg_prep<<<33, 256, 0, stream>>>(W_lin, W_res, weight, b_lin, bias, b_res,
                                     Bf, Ws, Cd);
    pcg_mfma<<<(N_NODES + 63) / 64, 256, 0, stream>>>(ndata, Bf, Ws, Cd, Gq, Pq);
    pcg_gather<<<N_NODES / 4, 256, 0, stream>>>(neighbors, Gq, Pq, out);
}

// Round 8
// 39.888 us; speedup vs baseline: 4.5606x; 4.5606x over previous
//
#include <hip/hip_runtime.h>
#include <math.h>

#define N_NODES 30000
#define K_NBR   16
#define C_IN    256
#define C_OUT   128
#define KS      9
#define S_MB    17
#define BR      32    // rows per mfma block (was 64 — halved for occupancy)

typedef __attribute__((ext_vector_type(4))) float f32x4;
typedef __attribute__((ext_vector_type(2))) float f32x2;
typedef __attribute__((ext_vector_type(8))) short bf16x8;

static __device__ __forceinline__ ushort f2bf(float f) {
    uint u = __builtin_bit_cast(uint, f);
    u += 0x7fffu + ((u >> 16) & 1u);          // round-to-nearest-even
    return (ushort)(u >> 16);
}

// ---------------------------------------------------------------------------
// Prep: blocks 0..31 convert stacked W (rows 0..127 = W_lin, 128..255 = W_res)
// into fragment-ordered bf16 Bf. Block 32 computes per-channel Ws/Cd.
// ---------------------------------------------------------------------------
__global__ __launch_bounds__(256)
void pcg_prep(const float* __restrict__ W_lin,
              const float* __restrict__ W_res,
              const float* __restrict__ weight,
              const float* __restrict__ b_lin,
              const float* __restrict__ bias,
              const float* __restrict__ b_res,
              ushort* __restrict__ Bf,
              float* __restrict__ Ws,
              float* __restrict__ Cd) {
    if (blockIdx.x == 32) {
        int d = threadIdx.x;
        if (d >= C_OUT) return;
        float freq = powf(10000.0f, -(float)(d & ~1) / (float)C_OUT);
        float ws = 0.f, p = 0.f;
        for (int s = 0; s < S_MB; ++s) {
            int idx = (int)floorf((float)s * (9.0f / 17.0f));
            ws += weight[d * KS + idx];
            float ang = (float)idx * freq;
            p += (d & 1) ? cosf(ang) : sinf(ang);
        }
        Ws[d] = ws;
        Cd[d] = ws * ((float)(K_NBR + 1) * b_lin[d] + p) + bias[d] + b_res[d];
        return;
    }
    const int tt     = blockIdx.x * 256 + threadIdx.x;   // 0..8191
    const int col_lo = tt & 15;
    const int ksub   = (tt >> 4) & 3;
    const int colhi  = (tt >> 6) & 15;
    const int kc     = tt >> 10;
    const int col    = colhi * 16 + col_lo;
    const int k0     = kc * 32 + ksub * 8;
    const float* Wr = (col < C_OUT)
        ? &W_lin[(size_t)col * C_IN + k0]
        : &W_res[(size_t)(col - C_OUT) * C_IN + k0];
    const f32x4 w0 = *reinterpret_cast<const f32x4*>(Wr);
    const f32x4 w1 = *reinterpret_cast<const f32x4*>(Wr + 4);
    ushort b[8] = { f2bf(w0.x), f2bf(w0.y), f2bf(w0.z), f2bf(w0.w),
                    f2bf(w1.x), f2bf(w1.y), f2bf(w1.z), f2bf(w1.w) };
    *reinterpret_cast<uint4*>(&Bf[(size_t)tt * 8]) =
        *reinterpret_cast<const uint4*>(b);
}

// ---------------------------------------------------------------------------
// MFMA GEMM + epilogue fold:
//   Gs[n][d] = Ws[d] * (ndata[n,:].W_lin[d,:])            (bf16, gathered)
//   Pc[n][d] = Gs + ndata[n,:].W_res[d,:] + Cd[d]         (bf16, per-node)
// Block: BR=32 rows x 256 stacked cols, 4 waves; wave w owns G cols
// w*32..+31 (cg 0,1) and R cols of the SAME d (cg 2,3) -> in-register fold.
// Grid 938 (~3.7 blocks/CU) for occupancy (R7: 469 blocks -> 10% occ).
// A staged f32->bf16 in LDS, fragment order, 16B-granule XOR swizzle
// (verified conflict-free in R7: SQ_LDS_BANK_CONFLICT = 0).
// ---------------------------------------------------------------------------
__global__ __launch_bounds__(256)
void pcg_mfma(const float* __restrict__ ndata,
              const ushort* __restrict__ Bf,
              const float* __restrict__ Ws,
              const float* __restrict__ Cd,
              ushort* __restrict__ Gs,
              ushort* __restrict__ Pc) {
    __shared__ short sA[8192];                 // 16 frags x 64 x 16B = 16 KB

    const int t  = threadIdx.x;
    const int n0 = blockIdx.x * BR;

    // ---- stage A tile: 4 x (two f32x4 -> one 16B ds_write_b128) ----
#pragma unroll
    for (int i = 0; i < 4; ++i) {
        const int v    = i * 256 + t;          // (row, kchunk) in 32 x 32
        const int row  = v >> 5;
        const int kch  = v & 31;
        f32x4 a0 = {0.f, 0.f, 0.f, 0.f}, a1 = {0.f, 0.f, 0.f, 0.f};
        if (n0 + row < N_NODES) {
            const float* p = &ndata[(size_t)(n0 + row) * C_IN + kch * 8];
            a0 = *reinterpret_cast<const f32x4*>(p);
            a1 = *reinterpret_cast<const f32x4*>(p + 4);
        }
        const int kc   = kch >> 2;
        const int ksub = kch & 3;
        const int f    = kc * 2 + (row >> 4);
        const int up   = (((row & 15) | (ksub << 4)) ^ ksub) ^ ((kc & 1) << 2);
        uint4 w;
        w.x = (uint)f2bf(a0.x) | ((uint)f2bf(a0.y) << 16);
        w.y = (uint)f2bf(a0.z) | ((uint)f2bf(a0.w) << 16);
        w.z = (uint)f2bf(a1.x) | ((uint)f2bf(a1.y) << 16);
        w.w = (uint)f2bf(a1.z) | ((uint)f2bf(a1.w) << 16);
        *reinterpret_cast<uint4*>(&sA[f * 512 + up * 8]) = w;
    }
    __syncthreads();

    const int wave = t >> 6;
    const int l    = t & 63;
    const int bu   = l ^ (l >> 4);             // base swizzled 16B-unit index

    // column-group -> stacked-column-high mapping (G,G,R,R for same d range)
    const int ch0 = 2 * wave;
    const int ch1 = 2 * wave + 1;
    const int ch2 = 8 + 2 * wave;
    const int ch3 = 9 + 2 * wave;

    f32x4 acc[2][4] = {};                       // [rg][cg]

#pragma unroll
    for (int kc = 0; kc < 8; ++kc) {
        const int ux = bu ^ ((kc & 1) << 2);
        bf16x8 a[2];
#pragma unroll
        for (int rg = 0; rg < 2; ++rg)
            a[rg] = *reinterpret_cast<const bf16x8*>(
                        &sA[(kc * 2 + rg) * 512 + ux * 8]);
        bf16x8 b[4];
        b[0] = *reinterpret_cast<const bf16x8*>(&Bf[((size_t)(kc * 16 + ch0) * 64 + l) * 8]);
        b[1] = *reinterpret_cast<const bf16x8*>(&Bf[((size_t)(kc * 16 + ch1) * 64 + l) * 8]);
        b[2] = *reinterpret_cast<const bf16x8*>(&Bf[((size_t)(kc * 16 + ch2) * 64 + l) * 8]);
        b[3] = *reinterpret_cast<const bf16x8*>(&Bf[((size_t)(kc * 16 + ch3) * 64 + l) * 8]);
#pragma unroll
        for (int rg = 0; rg < 2; ++rg)
#pragma unroll
            for (int cg = 0; cg < 4; ++cg)
                acc[rg][cg] = __builtin_amdgcn_mfma_f32_16x16x32_bf16(
                                  a[rg], b[cg], acc[rg][cg], 0, 0, 0);
    }

    // ---- epilogue: D layout col = lane&15, row = (lane>>4)*4 + reg ----
    const int cl  = l & 15;
    const int c0  = wave * 32 + cl;            // G col for cg 0 / R cg 2
    const int c1  = wave * 32 + 16 + cl;       // G col for cg 1 / R cg 3
    const float ws0 = Ws[c0], ws1 = Ws[c1];
    const float cd0 = Cd[c0], cd1 = Cd[c1];
    const int rl  = (l >> 4) * 4;
#pragma unroll
    for (int rg = 0; rg < 2; ++rg) {
#pragma unroll
        for (int j = 0; j < 4; ++j) {
            const int row = n0 + rg * 16 + rl + j;
            if (row < N_NODES) {
                const float gs0 = ws0 * acc[rg][0][j];
                const float gs1 = ws1 * acc[rg][1][j];
                Gs[(size_t)row * C_OUT + c0] = f2bf(gs0);
                Gs[(size_t)row * C_OUT + c1] = f2bf(gs1);
                Pc[(size_t)row * C_OUT + c0] = f2bf(gs0 + acc[rg][2][j] + cd0);
                Pc[(size_t)row * C_OUT + c1] = f2bf(gs1 + acc[rg][3][j] + cd1);
            }
        }
    }
}

// ---------------------------------------------------------------------------
// Gather: out[n][d] = Pc[n][d] + sum_k Gs[neighbors[n,k]][d]
// (R7: ~2.7 us, at its write floor — unchanged)
// ---------------------------------------------------------------------------
__global__ __launch_bounds__(256)
void pcg_gather(const int* __restrict__ neighbors,
                const ushort* __restrict__ Gs,
                const ushort* __restrict__ Pc,
                float* __restrict__ out) {
    __shared__ int snb[64];
    const int t = threadIdx.x;
    if (t < 64) snb[t] = neighbors[(size_t)blockIdx.x * 64 + t];
    __syncthreads();

    const int g = t >> 6;                      // node group 0..3
    const int l = t & 63;
    const int n = blockIdx.x * 4 + g;

    uint p = *reinterpret_cast<const uint*>(&Pc[(size_t)n * C_OUT + 2 * l]);
    float a0 = __builtin_bit_cast(float, p << 16);
    float a1 = __builtin_bit_cast(float, p & 0xffff0000u);

#pragma unroll
    for (int k = 0; k < K_NBR; ++k) {
        const int m = snb[g * 16 + k];
        uint v = *reinterpret_cast<const uint*>(&Gs[(size_t)m * C_OUT + 2 * l]);
        a0 += __builtin_bit_cast(float, v << 16);
        a1 += __builtin_bit_cast(float, v & 0xffff0000u);
    }

    f32x2 o = {a0, a1};
    *reinterpret_cast<f32x2*>(&out[(size_t)n * C_OUT + 2 * l]) = o;
}

// ---------------------------------------------------------------------------
extern "C" void kernel_launch(void* const* d_in, const int* in_sizes, int n_in,
                              void* d_out, int out_size, void* d_ws, size_t ws_size,
                              hipStream_t stream) {
    const float* ndata     = (const float*)d_in[0];
    const int*   neighbors = (const int*)  d_in[1];
    const float* W_lin     = (const float*)d_in[2];
    const float* b_lin     = (const float*)d_in[3];
    const float* weight    = (const float*)d_in[4];
    const float* bias      = (const float*)d_in[5];
    const float* W_res     = (const float*)d_in[6];
    const float* b_res     = (const float*)d_in[7];
    float* out = (float*)d_out;

    ushort* Bf = (ushort*)d_ws;                          // [8192][8] = 128 KB
    ushort* Gq = Bf + 65536;                             // Gs [N][128] = 7.68 MB
    ushort* Pq = Gq + (size_t)N_NODES * C_OUT;           // Pc [N][128] = 7.68 MB
    float*  Ws = (float*)(Pq + (size_t)N_NODES * C_OUT); // [128]
    float*  Cd = Ws + C_OUT;                             // [128]

    pcg_prep<<<33, 256, 0, stream>>>(W_lin, W_res, weight, b_lin, bias, b_res,
                                     Bf, Ws, Cd);
    pcg_mfma<<<(N_NODES + BR - 1) / BR, 256, 0, stream>>>(
        ndata, Bf, Ws, Cd, Gq, Pq);
    pcg_gather<<<N_NODES / 4, 256, 0, stream>>>(neighbors, Gq, Pq, out);
}